// Round 10
// baseline (357.593 us; speedup 1.0000x reference)
//
#include <hip/hip_runtime.h>
#include <math.h>

typedef __bf16 bf16;
typedef __bf16 bf16x8 __attribute__((ext_vector_type(8)));
typedef __bf16 bf16x4 __attribute__((ext_vector_type(4)));
typedef float f32x2 __attribute__((ext_vector_type(2)));
typedef float f32x4 __attribute__((ext_vector_type(4)));
typedef float f32x16 __attribute__((ext_vector_type(16)));
typedef int i32x4 __attribute__((ext_vector_type(4)));

constexpr int B_ = 8, S_ = 1024, D_ = 1024, H_ = 16, DK_ = 64;
constexpr int M_ = B_ * S_;                 // 8192
constexpr size_t A8 = (size_t)1 << 23;      // M_*D_ = 8388608
constexpr size_t W1 = (size_t)1 << 20;      // D_*D_ = 1048576
constexpr float QSCALE = 0.18033688011112042f;  // 0.125 * log2(e)

#if __has_builtin(__builtin_amdgcn_exp2f)
#define EXP2F(x) __builtin_amdgcn_exp2f(x)
#else
#define EXP2F(x) exp2f(x)
#endif
#if __has_builtin(__builtin_amdgcn_rcpf)
#define RCPF(x) __builtin_amdgcn_rcpf(x)
#else
#define RCPF(x) (1.0f / (x))
#endif

#define GAS(p) ((const __attribute__((address_space(1))) void*)(p))
#define LAS(p) ((__attribute__((address_space(3))) void*)(p))

__device__ __forceinline__ float xor32f(float v, int bpidx) {
    return __builtin_bit_cast(float,
        __builtin_amdgcn_ds_bpermute(bpidx, __builtin_bit_cast(int, v)));
}
__device__ __forceinline__ int xor32i(int v, int bpidx) {
    return __builtin_amdgcn_ds_bpermute(bpidx, v);
}
// Convention-free bf16 pair pack: even -> low 16, odd -> high 16 (C semantics).
// (v_cvt_pk_bf16_f32 asm was PROVEN wrong on this toolchain in r3->r4 A/B.)
__device__ __forceinline__ int pack_bf16(bf16 lo, bf16 hi) {
    return (int)(unsigned)__builtin_bit_cast(unsigned short, lo)
         | ((int)(unsigned)__builtin_bit_cast(unsigned short, hi) << 16);
}

struct F4Q { f32x4 a, b, c, d; };

// ---------------------------------------------------------------------------
// LEDGER (attn variants, measured):
//   r5/r9 scalar softmax + maskf C-init + no setprio     = 83-84 us  <- BEST
//   r7    packed softmax + maskf C-init + setprio        = 89.6 us
//   r8    packed softmax + scattered raw-mask mult       = 101.3 us
//   r6    launch_bounds(256,4)                           = 127 us (spills)
// Conclusions: packed softmax ~ +5 us (codegen), setprio ~ neutral,
// scattered per-lane mask loads ~ +12 us, occupancy bound -> spill disaster.
// attn in this file == r5/r9 verbatim.
// r10: mask_cvt fused into cvt_all when ws_size permits a dedicated maskf
// region (removes 1 dispatch + the qkv->mask->attn serialization); exact
// r9 fallback otherwise.
// ---------------------------------------------------------------------------

// mask permute body shared by fused and standalone paths
__device__ __forceinline__ void mask_cvt_body(
    int bx, int tid, const int* __restrict__ mask, float* __restrict__ mf)
{
    const int kt = bx & 15, qt = (bx >> 4) & 7, b = bx >> 7;
    const int w = tid >> 6, lane = tid & 63;
    const int hi = lane >> 5, l31 = lane & 31;
    const int q = qt * 128 + w * 32 + l31;

    const int* src = mask + ((size_t)b << 20) + (size_t)q * 1024 + kt * 64 + hi * 4;
    float* dst = mf + (size_t)bx * 8192 + w * 2048 + lane * 4;
#pragma unroll
    for (int blk = 0; blk < 2; ++blk)
#pragma unroll
        for (int rr = 0; rr < 4; ++rr) {
            int4 m = *(const int4*)(src + blk * 32 + rr * 8);
            f32x4 o = { m.x ? 0.f : -1e9f, m.y ? 0.f : -1e9f,
                        m.z ? 0.f : -1e9f, m.w ? 0.f : -1e9f };
            *(f32x4*)(dst + (blk * 4 + rr) * 256) = o;
        }
}

// ---------------------------------------------------------------------------
// Fused fp32->bf16 convert for q,k,v (A8 each) + 4 weight matrices (W1 each).
// Blocks >= 14336 (fused path only): mask -> additive f32 pre-permute.
// ---------------------------------------------------------------------------
__global__ __launch_bounds__(256) void cvt_all(
    const float* __restrict__ q, const float* __restrict__ k,
    const float* __restrict__ v, const float* __restrict__ w0,
    const float* __restrict__ w1, const float* __restrict__ w2,
    const float* __restrict__ w3, bf16* __restrict__ dst,
    const int* __restrict__ mask, float* __restrict__ mf)
{
    const int bid = blockIdx.x;
    if (bid >= 14336) {
        mask_cvt_body(bid - 14336, threadIdx.x, mask, mf);
        return;
    }
    size_t e = ((size_t)bid * 256 + threadIdx.x) * 8;
    const float* src;
    size_t off;
    if (e < 3 * A8) {
        int t = (int)(e >> 23);
        src = (t == 0) ? q : (t == 1) ? k : v;
        off = e & (A8 - 1);
    } else {
        size_t ew = e - 3 * A8;
        int t = (int)(ew >> 20);
        src = (t == 0) ? w0 : (t == 1) ? w1 : (t == 2) ? w2 : w3;
        off = ew & (W1 - 1);
    }
    float4 a = *(const float4*)(src + off);
    float4 b = *(const float4*)(src + off + 4);
    bf16x8 o = { (bf16)a.x, (bf16)a.y, (bf16)a.z, (bf16)a.w,
                 (bf16)b.x, (bf16)b.y, (bf16)b.z, (bf16)b.w };
    *(bf16x8*)(dst + e) = o;
}

// ---------------------------------------------------------------------------
// Standalone mask_cvt (fallback path when maskf must alias qb/kb; runs AFTER
// the QKV GEMM — do not reorder).
// ---------------------------------------------------------------------------
__global__ __launch_bounds__(256) void mask_cvt(
    const int* __restrict__ mask, float* __restrict__ mf)
{
    mask_cvt_body(blockIdx.x, threadIdx.x, mask, mf);
}

// ---------------------------------------------------------------------------
// Fused Q/K/V GEMM: one dispatch of 1536 blocks (3 x 512).
// which = blockIdx.x>>9 selects operand set (epilogue branch block-uniform).
// Q,K -> bf16 scatter [B,H,S,DK] (Q scaled); V -> bf16 scatter [B,H,DK,S].
// NOTE bid->XCD: blocks sharing an X-panel are 64 apart (same mod 8) -> same
// XCD L2 already; W is 2MB (L3-resident). Do NOT add a block swizzle here.
// ---------------------------------------------------------------------------
__global__ __launch_bounds__(256) void qkv_gemm(
    const bf16* __restrict__ qb, const bf16* __restrict__ kb,
    const bf16* __restrict__ vb, const bf16* __restrict__ wq,
    const bf16* __restrict__ wk, const bf16* __restrict__ wv,
    const float* __restrict__ bq, const float* __restrict__ bk,
    const float* __restrict__ bv, bf16* __restrict__ Qp,
    bf16* __restrict__ Kp, bf16* __restrict__ Vp, float qscale)
{
    constexpr int K = 1024;
    __shared__ bf16 As[128 * 32];
    __shared__ bf16 Bs[128 * 32];

    const int bid = blockIdx.x;
    const int which = bid >> 9;          // 0:Q 1:K 2:V
    const int gb = bid & 511;
    const bf16* X = which == 0 ? qb : which == 1 ? kb : vb;
    const bf16* W = which == 0 ? wq : which == 1 ? wk : wv;
    const float* bias = which == 0 ? bq : which == 1 ? bk : bv;
    bf16* outp = which == 0 ? Qp : which == 1 ? Kp : Vp;
    const float oscale = which == 0 ? qscale : 1.0f;

    const int tid  = threadIdx.x;
    const int lane = tid & 63;
    const int w    = tid >> 6;
    const int wm   = w & 1, wn = w >> 1;
    const int quad = lane >> 4, l15 = lane & 15;
    const int bm = (gb & 63) * 128, bn = (gb >> 6) * 128;

    f32x4 acc[4][4];
#pragma unroll
    for (int i = 0; i < 4; ++i)
#pragma unroll
        for (int j = 0; j < 4; ++j)
#pragma unroll
            for (int r = 0; r < 4; ++r) acc[i][j][r] = 0.f;

    const int lrow = lane >> 2;
    const int lcol = (lane & 3) * 8;

    for (int k0 = 0; k0 < K; k0 += 32) {
        __syncthreads();
#pragma unroll
        for (int i = 0; i < 2; ++i) {
            const int rbase = w * 16 + i * 64;
            __builtin_amdgcn_global_load_lds(
                GAS(X + (size_t)(bm + rbase + lrow) * K + k0 + lcol),
                LAS(As + rbase * 32), 16, 0, 0);
            __builtin_amdgcn_global_load_lds(
                GAS(W + (size_t)(bn + rbase + lrow) * K + k0 + lcol),
                LAS(Bs + rbase * 32), 16, 0, 0);
        }
        __syncthreads();

        bf16x8 a[4], b[4];
#pragma unroll
        for (int i = 0; i < 4; ++i)
            a[i] = *(const bf16x8*)(As + (wm * 64 + i * 16 + l15) * 32 + quad * 8);
#pragma unroll
        for (int j = 0; j < 4; ++j)
            b[j] = *(const bf16x8*)(Bs + (wn * 64 + j * 16 + l15) * 32 + quad * 8);
#pragma unroll
        for (int i = 0; i < 4; ++i)
#pragma unroll
            for (int j = 0; j < 4; ++j)
                acc[i][j] = __builtin_amdgcn_mfma_f32_16x16x32_bf16(
                    a[i], b[j], acc[i][j], 0, 0, 0);
    }

#pragma unroll
    for (int i = 0; i < 4; ++i) {
#pragma unroll
        for (int j = 0; j < 4; ++j) {
            const int n = bn + wn * 64 + j * 16 + l15;
            const float bs = bias[n];
            if (which == 2) {
                const int m0 = bm + wm * 64 + i * 16 + quad * 4;
                const int bb = m0 >> 10, s0 = m0 & 1023;
                const int h = n >> 6, dk = n & 63;
                bf16x4 o;
#pragma unroll
                for (int r = 0; r < 4; ++r) o[r] = (bf16)(acc[i][j][r] + bs);
                *(bf16x4*)(outp + (((size_t)(bb * 16 + h) * 64 + dk) << 10) + s0) = o;
            } else {
#pragma unroll
                for (int r = 0; r < 4; ++r) {
                    const int m = bm + wm * 64 + i * 16 + quad * 4 + r;
                    const int bb = m >> 10, s = m & 1023;
                    const int h = n >> 6, dk = n & 63;
                    outp[(((size_t)(bb * 16 + h)) * 1024 + s) * 64 + dk] =
                        (bf16)((acc[i][j][r] + bs) * oscale);
                }
            }
        }
    }
}

// ---------------------------------------------------------------------------
// Final projection GEMM: C = X @ W^T + bias, fp32 out [M,1024] (m97 recipe).
// ---------------------------------------------------------------------------
__global__ __launch_bounds__(256) void gemm_out(
    const bf16* __restrict__ X, const bf16* __restrict__ W,
    const float* __restrict__ bias, float* __restrict__ outv)
{
    constexpr int K = 1024;
    __shared__ bf16 As[128 * 32];
    __shared__ bf16 Bs[128 * 32];

    const int tid  = threadIdx.x;
    const int lane = tid & 63;
    const int w    = tid >> 6;
    const int wm   = w & 1, wn = w >> 1;
    const int quad = lane >> 4, l15 = lane & 15;
    const int bm = blockIdx.x * 128, bn = blockIdx.y * 128;

    f32x4 acc[4][4];
#pragma unroll
    for (int i = 0; i < 4; ++i)
#pragma unroll
        for (int j = 0; j < 4; ++j)
#pragma unroll
            for (int r = 0; r < 4; ++r) acc[i][j][r] = 0.f;

    const int lrow = lane >> 2;
    const int lcol = (lane & 3) * 8;

    for (int k0 = 0; k0 < K; k0 += 32) {
        __syncthreads();
#pragma unroll
        for (int i = 0; i < 2; ++i) {
            const int rbase = w * 16 + i * 64;
            __builtin_amdgcn_global_load_lds(
                GAS(X + (size_t)(bm + rbase + lrow) * K + k0 + lcol),
                LAS(As + rbase * 32), 16, 0, 0);
            __builtin_amdgcn_global_load_lds(
                GAS(W + (size_t)(bn + rbase + lrow) * K + k0 + lcol),
                LAS(Bs + rbase * 32), 16, 0, 0);
        }
        __syncthreads();

        bf16x8 a[4], b[4];
#pragma unroll
        for (int i = 0; i < 4; ++i)
            a[i] = *(const bf16x8*)(As + (wm * 64 + i * 16 + l15) * 32 + quad * 8);
#pragma unroll
        for (int j = 0; j < 4; ++j)
            b[j] = *(const bf16x8*)(Bs + (wn * 64 + j * 16 + l15) * 32 + quad * 8);
#pragma unroll
        for (int i = 0; i < 4; ++i)
#pragma unroll
            for (int j = 0; j < 4; ++j)
                acc[i][j] = __builtin_amdgcn_mfma_f32_16x16x32_bf16(
                    a[i], b[j], acc[i][j], 0, 0, 0);
    }

#pragma unroll
    for (int i = 0; i < 4; ++i)
#pragma unroll
        for (int j = 0; j < 4; ++j) {
            const int n = bn + wn * 64 + j * 16 + l15;
            const float bs = bias[n];
#pragma unroll
            for (int r = 0; r < 4; ++r) {
                const int m = bm + wm * 64 + i * 16 + quad * 4 + r;
                outv[(size_t)m * 1024 + n] = acc[i][j][r] + bs;
            }
        }
}

// ---------------------------------------------------------------------------
// MFMA flash attention — r5/r9 configuration VERBATIM (measured 83-84 us):
// scalar softmax chains, maskf C-frag init with one-tile-ahead register
// prefetch, 2-bpermute cross-lane exchange, NO setprio, NO occupancy bound.
// ---------------------------------------------------------------------------
__global__ __launch_bounds__(256) void attn_mfma(
    const bf16* __restrict__ Q, const bf16* __restrict__ Kt,
    const bf16* __restrict__ Vt, const float* __restrict__ mf,
    bf16* __restrict__ out)
{
    __shared__ bf16 smem[2 * 2 * 4096];   // [buf][K|V][64 rows x 128B]

    const int tid  = threadIdx.x;
    const int lane = tid & 63;
    const int w    = tid >> 6;
    const int hi   = lane >> 5, l31 = lane & 31;

    // bijective XCD swizzle: each XCD gets one full batch b (128 blocks)
    const int wid = (blockIdx.x & 7) * 128 + (blockIdx.x >> 3);
    const int qt = wid & 7;
    const int h  = (wid >> 3) & 15;
    const int b  = wid >> 7;

    const bf16* Qg  = Q + ((size_t)((b * H_ + h) * S_) + qt * 128 + w * 32) * DK_;
    const char* Kgh = (const char*)(Kt + (size_t)(b * H_ + h) * S_ * DK_);
    const char* Vgh = (const char*)(Vt + ((size_t)(b * H_ + h) << 16));
    const float* mtb = mf + (size_t)((b * 8 + qt) * 16) * 8192 + w * 2048 + lane * 4;

    // staging source offsets (inverse-XOR-swizzled global, linear LDS dest)
    const int tA = tid,        rA = tA >> 3, cA = (tA & 7) * 16;
    const int tB = 256 + tid,  rB = tB >> 3, cB = (tB & 7) * 16;
    const int kSrcA = rA * 128  + (cA ^ ((rA & 7) << 4));
    const int kSrcB = rB * 128  + (cB ^ ((rB & 7) << 4));
    const int vSrcA = rA * 2048 + (cA ^ ((rA & 7) << 4));
    const int vSrcB = rB * 2048 + (cB ^ ((rB & 7) << 4));

    auto stage = [&](int buf, int tkt) {
        bf16* Ks = smem + buf * 8192;
        bf16* Vs = Ks + 4096;
        const char* kg = Kgh + (size_t)tkt * 8192;
        const char* vg = Vgh + (size_t)tkt * 128;
        __builtin_amdgcn_global_load_lds(GAS(kg + kSrcA), LAS(Ks + w * 512),        16, 0, 0);
        __builtin_amdgcn_global_load_lds(GAS(kg + kSrcB), LAS(Ks + 2048 + w * 512), 16, 0, 0);
        __builtin_amdgcn_global_load_lds(GAS(vg + vSrcA), LAS(Vs + w * 512),        16, 0, 0);
        __builtin_amdgcn_global_load_lds(GAS(vg + vSrcB), LAS(Vs + 2048 + w * 512), 16, 0, 0);
    };

    stage(0, 0);

    // Q fragments: lane holds Q[q = l31][dk = ks*16 + hi*8 + e]
    bf16x8 qf[4];
#pragma unroll
    for (int ks = 0; ks < 4; ++ks)
        qf[ks] = *(const bf16x8*)(Qg + (size_t)l31 * 64 + ks * 16 + hi * 8);

    // mask prefetch: tile 0
    f32x4 mreg[8];
#pragma unroll
    for (int i = 0; i < 8; ++i) mreg[i] = *(const f32x4*)(mtb + i * 256);

    f32x16 O0, O1;
#pragma unroll
    for (int r = 0; r < 16; ++r) { O0[r] = 0.f; O1[r] = 0.f; }
    float mrow = -INFINITY, lrowv = 0.f;
    const int bpidx = (lane ^ 32) << 2;
    const int swz = (l31 & 7) << 4;

    __syncthreads();

#pragma unroll 2
    for (int kt = 0; kt < 16; ++kt) {
        const int buf = kt & 1;
        const bf16* Ks = smem + buf * 8192;
        const bf16* Vs = Ks + 4096;
        const char* KsB = (const char*)Ks;
        const char* VsB = (const char*)Vs;

        // acc init = additive mask (prefetched registers)
        F4Q mq0 = { mreg[0], mreg[1], mreg[2], mreg[3] };
        F4Q mq1 = { mreg[4], mreg[5], mreg[6], mreg[7] };
        f32x16 acc0 = __builtin_bit_cast(f32x16, mq0);
        f32x16 acc1 = __builtin_bit_cast(f32x16, mq1);

        // prefetch next tile's mask (latency hidden under this tile's compute)
        if (kt < 15) {
            const float* mkn = mtb + (size_t)(kt + 1) * 8192;
#pragma unroll
            for (int i = 0; i < 8; ++i) mreg[i] = *(const f32x4*)(mkn + i * 256);
        }

        if (kt + 1 < 16) stage(buf ^ 1, kt + 1);

        // ---- S^T = K Q^T : lane holds P[q=l31][k = 32*blk + (r&3)+8*(r>>2)+4*hi]
#pragma unroll
        for (int ks = 0; ks < 4; ++ks) {
            const int cb = ks * 32 + hi * 16;
            bf16x8 k0 = *(const bf16x8*)(KsB + l31 * 128        + (cb ^ swz));
            bf16x8 k1 = *(const bf16x8*)(KsB + (l31 + 32) * 128 + (cb ^ swz));
            acc0 = __builtin_amdgcn_mfma_f32_32x32x16_bf16(k0, qf[ks], acc0, 0, 0, 0);
            acc1 = __builtin_amdgcn_mfma_f32_32x32x16_bf16(k1, qf[ks], acc1, 0, 0, 0);
        }

        // ---- per-lane row max over 32 values, then cross-32 combine ----
        float red[8];
#pragma unroll
        for (int i = 0; i < 8; ++i)
            red[i] = fmaxf(fmaxf(acc0[i], acc0[i + 8]), fmaxf(acc1[i], acc1[i + 8]));
#pragma unroll
        for (int i = 0; i < 4; ++i) red[i] = fmaxf(red[i], red[i + 4]);
        float mx = fmaxf(fmaxf(red[0], red[1]), fmaxf(red[2], red[3]));
        mx = fmaxf(mx, xor32f(mx, bpidx));

        // ---- defer-max (T13): rescale only when max grows past threshold ----
        if (__any(mx > mrow + 8.0f)) {
            const float mn = fmaxf(mrow, mx);
            const float alpha = EXP2F(mrow - mn);
            mrow = mn;
            lrowv *= alpha;
#pragma unroll
            for (int r = 0; r < 16; ++r) { O0[r] *= alpha; O1[r] *= alpha; }
        }

        // ---- p = exp2(s - m) ----
#pragma unroll
        for (int r = 0; r < 16; ++r) acc0[r] = EXP2F(acc0[r] - mrow);
#pragma unroll
        for (int r = 0; r < 16; ++r) acc1[r] = EXP2F(acc1[r] - mrow);

        // ---- P -> bf16 via explicit casts; row-sum from ROUNDED values ----
        int wd0[8], wd1[8];
        float ps = 0.f;
#pragma unroll
        for (int s = 0; s < 8; ++s) {
            bf16 e0 = (bf16)acc0[2 * s], o0 = (bf16)acc0[2 * s + 1];
            bf16 e1 = (bf16)acc1[2 * s], o1 = (bf16)acc1[2 * s + 1];
            ps += (float)e0 + (float)o0 + (float)e1 + (float)o1;
            wd0[s] = pack_bf16(e0, o0);
            wd1[s] = pack_bf16(e1, o1);
        }
        ps += xor32f(ps, bpidx);
        lrowv += ps;

        // ---- build PV B-frag words: cross-lane^32 exchange, 2 bpermutes/ks
        //      (pre-select sent value: hi lane sends p0/p1, lo lane sends p2/p3)
        //      word t must hold keys {ks*16 + hi*8 + 2t, +1}
#pragma unroll
        for (int ks = 0; ks < 4; ++ks) {
            const int s0 = (ks & 1) * 4;
            int p0, p1, p2, p3;
            if (ks < 2) { p0 = wd0[s0]; p1 = wd0[s0 + 1]; p2 = wd0[s0 + 2]; p3 = wd0[s0 + 3]; }
            else        { p0 = wd1[s0]; p1 = wd1[s0 + 1]; p2 = wd1[s0 + 2]; p3 = wd1[s0 + 3]; }
            const int rx = xor32i(hi ? p0 : p2, bpidx);  // lo gets partner p0; hi gets partner p2
            const int ry = xor32i(hi ? p1 : p3, bpidx);  // lo gets partner p1; hi gets partner p3
            i32x4 pw = { hi ? rx : p0, hi ? ry : p1, hi ? p2 : rx, hi ? p3 : ry };
            bf16x8 pa = __builtin_bit_cast(bf16x8, pw);

            const int cb = ks * 32 + hi * 16;
            bf16x8 v0 = *(const bf16x8*)(VsB + l31 * 128        + (cb ^ swz));
            bf16x8 v1 = *(const bf16x8*)(VsB + (l31 + 32) * 128 + (cb ^ swz));
            O0 = __builtin_amdgcn_mfma_f32_32x32x16_bf16(v0, pa, O0, 0, 0, 0);
            O1 = __builtin_amdgcn_mfma_f32_32x32x16_bf16(v1, pa, O1, 0, 0, 0);
        }
        __syncthreads();
    }

    // ---- epilogue: per-lane normalize, packed bf16x4 stores ----
    const float rinv = RCPF(lrowv);
    bf16* og = out + ((size_t)b * S_ + qt * 128 + w * 32 + l31) * D_ + h * DK_;
#pragma unroll
    for (int rr = 0; rr < 4; ++rr) {
        bf16x4 o0 = { (bf16)(O0[rr * 4 + 0] * rinv), (bf16)(O0[rr * 4 + 1] * rinv),
                      (bf16)(O0[rr * 4 + 2] * rinv), (bf16)(O0[rr * 4 + 3] * rinv) };
        bf16x4 o1 = { (bf16)(O1[rr * 4 + 0] * rinv), (bf16)(O1[rr * 4 + 1] * rinv),
                      (bf16)(O1[rr * 4 + 2] * rinv), (bf16)(O1[rr * 4 + 3] * rinv) };
        *(bf16x4*)(og + rr * 8 + hi * 4)      = o0;
        *(bf16x4*)(og + 32 + rr * 8 + hi * 4) = o1;
    }
}

// ---------------------------------------------------------------------------
extern "C" void kernel_launch(void* const* d_in, const int* in_sizes, int n_in,
                              void* d_out, int out_size, void* d_ws, size_t ws_size,
                              hipStream_t stream) {
    const float* q    = (const float*)d_in[0];
    const float* k    = (const float*)d_in[1];
    const float* v    = (const float*)d_in[2];
    const int*   mask = (const int*)d_in[3];
    const float* WQw  = (const float*)d_in[4];
    const float* WQb  = (const float*)d_in[5];
    const float* WKw  = (const float*)d_in[6];
    const float* WKb  = (const float*)d_in[7];
    const float* WVw  = (const float*)d_in[8];
    const float* WVb  = (const float*)d_in[9];
    const float* WOw  = (const float*)d_in[10];
    const float* WOb  = (const float*)d_in[11];

    bf16* ws = (bf16*)d_ws;
    bf16* qb  = ws;              // A8
    bf16* kb  = qb + A8;         // A8
    bf16* vb  = kb + A8;         // A8  (later aliased by AO)
    bf16* wqb = vb + A8;         // W1 x4
    bf16* wkb = wqb + W1;
    bf16* wvb = wkb + W1;
    bf16* wob = wvb + W1;
    bf16* Qp  = wob + W1;        // [B,H,S,DK]
    bf16* Kp  = Qp + A8;         // [B,H,S,DK]
    bf16* Vp  = Kp + A8;         // [B,H,DK,S] transposed
    bf16* AO  = vb;              // alias: vb dead after V-GEMM

    // maskf placement: dedicated region after Vp if workspace permits
    // (fused path: mask permute rides in cvt_all, one fewer dispatch and no
    // qkv->mask serialization).  Fallback: alias qb/kb + separate mask_cvt
    // after the QKV GEMM (exact r9 behavior).
    const size_t base_bf16 = 6 * A8 + 4 * W1;              // through Vp
    const size_t need = base_bf16 * sizeof(bf16) + A8 * sizeof(float);
    const bool fused_mask = (ws_size >= need);
    float* maskf = fused_mask ? (float*)(ws + base_bf16) : (float*)qb;

    cvt_all<<<dim3(fused_mask ? 15360 : 14336), 256, 0, stream>>>(
        q, k, v, WQw, WKw, WVw, WOw, ws, mask, maskf);

    qkv_gemm<<<dim3(1536), 256, 0, stream>>>(qb, kb, vb, wqb, wkb, wvb,
                                             WQb, WKb, WVb, Qp, Kp, Vp, QSCALE);

    if (!fused_mask)
        mask_cvt<<<dim3(1024), 256, 0, stream>>>(mask, maskf);

    attn_mfma<<<dim3(1024), 256, 0, stream>>>(Qp, Kp, Vp, maskf, AO);

    gemm_out<<<dim3(M_ / 128, D_ / 128), 256, 0, stream>>>(AO, wob, WOb, (float*)d_out);
}

// Round 11
// 349.580 us; speedup vs baseline: 1.0229x; 1.0229x over previous
//
#include <hip/hip_runtime.h>
#include <math.h>

typedef __bf16 bf16;
typedef __bf16 bf16x8 __attribute__((ext_vector_type(8)));
typedef __bf16 bf16x4 __attribute__((ext_vector_type(4)));
typedef float f32x2 __attribute__((ext_vector_type(2)));
typedef float f32x4 __attribute__((ext_vector_type(4)));
typedef float f32x16 __attribute__((ext_vector_type(16)));
typedef int i32x4 __attribute__((ext_vector_type(4)));

constexpr int B_ = 8, S_ = 1024, D_ = 1024, H_ = 16, DK_ = 64;
constexpr int M_ = B_ * S_;                 // 8192
constexpr size_t A8 = (size_t)1 << 23;      // M_*D_ = 8388608
constexpr size_t W1 = (size_t)1 << 20;      // D_*D_ = 1048576
constexpr float QSCALE = 0.18033688011112042f;  // 0.125 * log2(e)

#if __has_builtin(__builtin_amdgcn_exp2f)
#define EXP2F(x) __builtin_amdgcn_exp2f(x)
#else
#define EXP2F(x) exp2f(x)
#endif
#if __has_builtin(__builtin_amdgcn_rcpf)
#define RCPF(x) __builtin_amdgcn_rcpf(x)
#else
#define RCPF(x) (1.0f / (x))
#endif

#define GAS(p) ((const __attribute__((address_space(1))) void*)(p))
#define LAS(p) ((__attribute__((address_space(3))) void*)(p))

__device__ __forceinline__ float xor32f(float v, int bpidx) {
    return __builtin_bit_cast(float,
        __builtin_amdgcn_ds_bpermute(bpidx, __builtin_bit_cast(int, v)));
}
__device__ __forceinline__ int xor32i(int v, int bpidx) {
    return __builtin_amdgcn_ds_bpermute(bpidx, v);
}
// Convention-free bf16 pair pack: even -> low 16, odd -> high 16 (C semantics).
// (v_cvt_pk_bf16_f32 asm was PROVEN wrong on this toolchain in r3->r4 A/B.)
__device__ __forceinline__ int pack_bf16(bf16 lo, bf16 hi) {
    return (int)(unsigned)__builtin_bit_cast(unsigned short, lo)
         | ((int)(unsigned)__builtin_bit_cast(unsigned short, hi) << 16);
}

struct F4Q { f32x4 a, b, c, d; };

// ---------------------------------------------------------------------------
// LEDGER (measured):
//  attn variants:
//   r5/r9/r10 scalar softmax + maskf C-init + no setprio = 82.5-84 us <- BEST
//   r7        packed softmax + setprio                   = 89.6 us
//   r8        packed softmax + scattered raw-mask mult   = 101.3 us
//   r6        launch_bounds(256,4)                       = 127 us (spills)
//  pipeline variants:
//   r9  qkv fused, standalone mask_cvt                   = 350.7 us <- BEST
//   r10 mask_cvt fused into cvt_all (ws-gated)           = 357.6 us (null/neg)
// Conclusions: packed softmax +5us (codegen), setprio ~neutral, scattered
// mask +12us, occupancy bound -> spill disaster, mask-fusion not worth it.
// GEMM levers at the m97 128x128 structure are catalog-null (T2 needs
// 8-phase; dbuf/BK>=64/bigger tiles regress).  This file == r9 exact.
// ---------------------------------------------------------------------------

// ---------------------------------------------------------------------------
// Fused fp32->bf16 convert for q,k,v (A8 each) + 4 weight matrices (W1 each).
// ---------------------------------------------------------------------------
__global__ __launch_bounds__(256) void cvt_all(
    const float* __restrict__ q, const float* __restrict__ k,
    const float* __restrict__ v, const float* __restrict__ w0,
    const float* __restrict__ w1, const float* __restrict__ w2,
    const float* __restrict__ w3, bf16* __restrict__ dst)
{
    size_t e = ((size_t)blockIdx.x * 256 + threadIdx.x) * 8;
    const float* src;
    size_t off;
    if (e < 3 * A8) {
        int t = (int)(e >> 23);
        src = (t == 0) ? q : (t == 1) ? k : v;
        off = e & (A8 - 1);
    } else {
        size_t ew = e - 3 * A8;
        int t = (int)(ew >> 20);
        src = (t == 0) ? w0 : (t == 1) ? w1 : (t == 2) ? w2 : w3;
        off = ew & (W1 - 1);
    }
    float4 a = *(const float4*)(src + off);
    float4 b = *(const float4*)(src + off + 4);
    bf16x8 o = { (bf16)a.x, (bf16)a.y, (bf16)a.z, (bf16)a.w,
                 (bf16)b.x, (bf16)b.y, (bf16)b.z, (bf16)b.w };
    *(bf16x8*)(dst + e) = o;
}

// ---------------------------------------------------------------------------
// Mask -> additive f32 (-1e9 / 0), pre-permuted into 32x32 MFMA C-frag order.
// Runs AFTER the QKV GEMM (maskf aliases qb/kb) — do not fuse or reorder.
// ---------------------------------------------------------------------------
__global__ __launch_bounds__(256) void mask_cvt(
    const int* __restrict__ mask, float* __restrict__ mf)
{
    const int bx = blockIdx.x;               // ((b*8+qt)*16+kt)
    const int kt = bx & 15, qt = (bx >> 4) & 7, b = bx >> 7;
    const int tid = threadIdx.x;
    const int w = tid >> 6, lane = tid & 63;
    const int hi = lane >> 5, l31 = lane & 31;
    const int q = qt * 128 + w * 32 + l31;

    const int* src = mask + ((size_t)b << 20) + (size_t)q * 1024 + kt * 64 + hi * 4;
    float* dst = mf + (size_t)bx * 8192 + w * 2048 + lane * 4;
#pragma unroll
    for (int blk = 0; blk < 2; ++blk)
#pragma unroll
        for (int rr = 0; rr < 4; ++rr) {
            int4 m = *(const int4*)(src + blk * 32 + rr * 8);
            f32x4 o = { m.x ? 0.f : -1e9f, m.y ? 0.f : -1e9f,
                        m.z ? 0.f : -1e9f, m.w ? 0.f : -1e9f };
            *(f32x4*)(dst + (blk * 4 + rr) * 256) = o;
        }
}

// ---------------------------------------------------------------------------
// Fused Q/K/V GEMM: one dispatch of 1536 blocks (3 x 512).
// which = blockIdx.x>>9 selects operand set (epilogue branch block-uniform).
// Q,K -> bf16 scatter [B,H,S,DK] (Q scaled); V -> bf16 scatter [B,H,DK,S].
// NOTE bid->XCD: blocks sharing an X-panel are 64 apart (same mod 8) -> same
// XCD L2 already; W is 2MB (L3-resident). Do NOT add a block swizzle here.
// ---------------------------------------------------------------------------
__global__ __launch_bounds__(256) void qkv_gemm(
    const bf16* __restrict__ qb, const bf16* __restrict__ kb,
    const bf16* __restrict__ vb, const bf16* __restrict__ wq,
    const bf16* __restrict__ wk, const bf16* __restrict__ wv,
    const float* __restrict__ bq, const float* __restrict__ bk,
    const float* __restrict__ bv, bf16* __restrict__ Qp,
    bf16* __restrict__ Kp, bf16* __restrict__ Vp, float qscale)
{
    constexpr int K = 1024;
    __shared__ bf16 As[128 * 32];
    __shared__ bf16 Bs[128 * 32];

    const int bid = blockIdx.x;
    const int which = bid >> 9;          // 0:Q 1:K 2:V
    const int gb = bid & 511;
    const bf16* X = which == 0 ? qb : which == 1 ? kb : vb;
    const bf16* W = which == 0 ? wq : which == 1 ? wk : wv;
    const float* bias = which == 0 ? bq : which == 1 ? bk : bv;
    bf16* outp = which == 0 ? Qp : which == 1 ? Kp : Vp;
    const float oscale = which == 0 ? qscale : 1.0f;

    const int tid  = threadIdx.x;
    const int lane = tid & 63;
    const int w    = tid >> 6;
    const int wm   = w & 1, wn = w >> 1;
    const int quad = lane >> 4, l15 = lane & 15;
    const int bm = (gb & 63) * 128, bn = (gb >> 6) * 128;

    f32x4 acc[4][4];
#pragma unroll
    for (int i = 0; i < 4; ++i)
#pragma unroll
        for (int j = 0; j < 4; ++j)
#pragma unroll
            for (int r = 0; r < 4; ++r) acc[i][j][r] = 0.f;

    const int lrow = lane >> 2;
    const int lcol = (lane & 3) * 8;

    for (int k0 = 0; k0 < K; k0 += 32) {
        __syncthreads();
#pragma unroll
        for (int i = 0; i < 2; ++i) {
            const int rbase = w * 16 + i * 64;
            __builtin_amdgcn_global_load_lds(
                GAS(X + (size_t)(bm + rbase + lrow) * K + k0 + lcol),
                LAS(As + rbase * 32), 16, 0, 0);
            __builtin_amdgcn_global_load_lds(
                GAS(W + (size_t)(bn + rbase + lrow) * K + k0 + lcol),
                LAS(Bs + rbase * 32), 16, 0, 0);
        }
        __syncthreads();

        bf16x8 a[4], b[4];
#pragma unroll
        for (int i = 0; i < 4; ++i)
            a[i] = *(const bf16x8*)(As + (wm * 64 + i * 16 + l15) * 32 + quad * 8);
#pragma unroll
        for (int j = 0; j < 4; ++j)
            b[j] = *(const bf16x8*)(Bs + (wn * 64 + j * 16 + l15) * 32 + quad * 8);
#pragma unroll
        for (int i = 0; i < 4; ++i)
#pragma unroll
            for (int j = 0; j < 4; ++j)
                acc[i][j] = __builtin_amdgcn_mfma_f32_16x16x32_bf16(
                    a[i], b[j], acc[i][j], 0, 0, 0);
    }

#pragma unroll
    for (int i = 0; i < 4; ++i) {
#pragma unroll
        for (int j = 0; j < 4; ++j) {
            const int n = bn + wn * 64 + j * 16 + l15;
            const float bs = bias[n];
            if (which == 2) {
                const int m0 = bm + wm * 64 + i * 16 + quad * 4;
                const int bb = m0 >> 10, s0 = m0 & 1023;
                const int h = n >> 6, dk = n & 63;
                bf16x4 o;
#pragma unroll
                for (int r = 0; r < 4; ++r) o[r] = (bf16)(acc[i][j][r] + bs);
                *(bf16x4*)(outp + (((size_t)(bb * 16 + h) * 64 + dk) << 10) + s0) = o;
            } else {
#pragma unroll
                for (int r = 0; r < 4; ++r) {
                    const int m = bm + wm * 64 + i * 16 + quad * 4 + r;
                    const int bb = m >> 10, s = m & 1023;
                    const int h = n >> 6, dk = n & 63;
                    outp[(((size_t)(bb * 16 + h)) * 1024 + s) * 64 + dk] =
                        (bf16)((acc[i][j][r] + bs) * oscale);
                }
            }
        }
    }
}

// ---------------------------------------------------------------------------
// Final projection GEMM: C = X @ W^T + bias, fp32 out [M,1024] (m97 recipe).
// ---------------------------------------------------------------------------
__global__ __launch_bounds__(256) void gemm_out(
    const bf16* __restrict__ X, const bf16* __restrict__ W,
    const float* __restrict__ bias, float* __restrict__ outv)
{
    constexpr int K = 1024;
    __shared__ bf16 As[128 * 32];
    __shared__ bf16 Bs[128 * 32];

    const int tid  = threadIdx.x;
    const int lane = tid & 63;
    const int w    = tid >> 6;
    const int wm   = w & 1, wn = w >> 1;
    const int quad = lane >> 4, l15 = lane & 15;
    const int bm = blockIdx.x * 128, bn = blockIdx.y * 128;

    f32x4 acc[4][4];
#pragma unroll
    for (int i = 0; i < 4; ++i)
#pragma unroll
        for (int j = 0; j < 4; ++j)
#pragma unroll
            for (int r = 0; r < 4; ++r) acc[i][j][r] = 0.f;

    const int lrow = lane >> 2;
    const int lcol = (lane & 3) * 8;

    for (int k0 = 0; k0 < K; k0 += 32) {
        __syncthreads();
#pragma unroll
        for (int i = 0; i < 2; ++i) {
            const int rbase = w * 16 + i * 64;
            __builtin_amdgcn_global_load_lds(
                GAS(X + (size_t)(bm + rbase + lrow) * K + k0 + lcol),
                LAS(As + rbase * 32), 16, 0, 0);
            __builtin_amdgcn_global_load_lds(
                GAS(W + (size_t)(bn + rbase + lrow) * K + k0 + lcol),
                LAS(Bs + rbase * 32), 16, 0, 0);
        }
        __syncthreads();

        bf16x8 a[4], b[4];
#pragma unroll
        for (int i = 0; i < 4; ++i)
            a[i] = *(const bf16x8*)(As + (wm * 64 + i * 16 + l15) * 32 + quad * 8);
#pragma unroll
        for (int j = 0; j < 4; ++j)
            b[j] = *(const bf16x8*)(Bs + (wn * 64 + j * 16 + l15) * 32 + quad * 8);
#pragma unroll
        for (int i = 0; i < 4; ++i)
#pragma unroll
            for (int j = 0; j < 4; ++j)
                acc[i][j] = __builtin_amdgcn_mfma_f32_16x16x32_bf16(
                    a[i], b[j], acc[i][j], 0, 0, 0);
    }

#pragma unroll
    for (int i = 0; i < 4; ++i)
#pragma unroll
        for (int j = 0; j < 4; ++j) {
            const int n = bn + wn * 64 + j * 16 + l15;
            const float bs = bias[n];
#pragma unroll
            for (int r = 0; r < 4; ++r) {
                const int m = bm + wm * 64 + i * 16 + quad * 4 + r;
                outv[(size_t)m * 1024 + n] = acc[i][j][r] + bs;
            }
        }
}

// ---------------------------------------------------------------------------
// MFMA flash attention — r5/r9 configuration VERBATIM (measured 82.5-84 us):
// scalar softmax chains, maskf C-frag init with one-tile-ahead register
// prefetch, 2-bpermute cross-lane exchange, NO setprio, NO occupancy bound.
// ---------------------------------------------------------------------------
__global__ __launch_bounds__(256) void attn_mfma(
    const bf16* __restrict__ Q, const bf16* __restrict__ Kt,
    const bf16* __restrict__ Vt, const float* __restrict__ mf,
    bf16* __restrict__ out)
{
    __shared__ bf16 smem[2 * 2 * 4096];   // [buf][K|V][64 rows x 128B]

    const int tid  = threadIdx.x;
    const int lane = tid & 63;
    const int w    = tid >> 6;
    const int hi   = lane >> 5, l31 = lane & 31;

    // bijective XCD swizzle: each XCD gets one full batch b (128 blocks)
    const int wid = (blockIdx.x & 7) * 128 + (blockIdx.x >> 3);
    const int qt = wid & 7;
    const int h  = (wid >> 3) & 15;
    const int b  = wid >> 7;

    const bf16* Qg  = Q + ((size_t)((b * H_ + h) * S_) + qt * 128 + w * 32) * DK_;
    const char* Kgh = (const char*)(Kt + (size_t)(b * H_ + h) * S_ * DK_);
    const char* Vgh = (const char*)(Vt + ((size_t)(b * H_ + h) << 16));
    const float* mtb = mf + (size_t)((b * 8 + qt) * 16) * 8192 + w * 2048 + lane * 4;

    // staging source offsets (inverse-XOR-swizzled global, linear LDS dest)
    const int tA = tid,        rA = tA >> 3, cA = (tA & 7) * 16;
    const int tB = 256 + tid,  rB = tB >> 3, cB = (tB & 7) * 16;
    const int kSrcA = rA * 128  + (cA ^ ((rA & 7) << 4));
    const int kSrcB = rB * 128  + (cB ^ ((rB & 7) << 4));
    const int vSrcA = rA * 2048 + (cA ^ ((rA & 7) << 4));
    const int vSrcB = rB * 2048 + (cB ^ ((rB & 7) << 4));

    auto stage = [&](int buf, int tkt) {
        bf16* Ks = smem + buf * 8192;
        bf16* Vs = Ks + 4096;
        const char* kg = Kgh + (size_t)tkt * 8192;
        const char* vg = Vgh + (size_t)tkt * 128;
        __builtin_amdgcn_global_load_lds(GAS(kg + kSrcA), LAS(Ks + w * 512),        16, 0, 0);
        __builtin_amdgcn_global_load_lds(GAS(kg + kSrcB), LAS(Ks + 2048 + w * 512), 16, 0, 0);
        __builtin_amdgcn_global_load_lds(GAS(vg + vSrcA), LAS(Vs + w * 512),        16, 0, 0);
        __builtin_amdgcn_global_load_lds(GAS(vg + vSrcB), LAS(Vs + 2048 + w * 512), 16, 0, 0);
    };

    stage(0, 0);

    // Q fragments: lane holds Q[q = l31][dk = ks*16 + hi*8 + e]
    bf16x8 qf[4];
#pragma unroll
    for (int ks = 0; ks < 4; ++ks)
        qf[ks] = *(const bf16x8*)(Qg + (size_t)l31 * 64 + ks * 16 + hi * 8);

    // mask prefetch: tile 0
    f32x4 mreg[8];
#pragma unroll
    for (int i = 0; i < 8; ++i) mreg[i] = *(const f32x4*)(mtb + i * 256);

    f32x16 O0, O1;
#pragma unroll
    for (int r = 0; r < 16; ++r) { O0[r] = 0.f; O1[r] = 0.f; }
    float mrow = -INFINITY, lrowv = 0.f;
    const int bpidx = (lane ^ 32) << 2;
    const int swz = (l31 & 7) << 4;

    __syncthreads();

#pragma unroll 2
    for (int kt = 0; kt < 16; ++kt) {
        const int buf = kt & 1;
        const bf16* Ks = smem + buf * 8192;
        const bf16* Vs = Ks + 4096;
        const char* KsB = (const char*)Ks;
        const char* VsB = (const char*)Vs;

        // acc init = additive mask (prefetched registers)
        F4Q mq0 = { mreg[0], mreg[1], mreg[2], mreg[3] };
        F4Q mq1 = { mreg[4], mreg[5], mreg[6], mreg[7] };
        f32x16 acc0 = __builtin_bit_cast(f32x16, mq0);
        f32x16 acc1 = __builtin_bit_cast(f32x16, mq1);

        // prefetch next tile's mask (latency hidden under this tile's compute)
        if (kt < 15) {
            const float* mkn = mtb + (size_t)(kt + 1) * 8192;
#pragma unroll
            for (int i = 0; i < 8; ++i) mreg[i] = *(const f32x4*)(mkn + i * 256);
        }

        if (kt + 1 < 16) stage(buf ^ 1, kt + 1);

        // ---- S^T = K Q^T : lane holds P[q=l31][k = 32*blk + (r&3)+8*(r>>2)+4*hi]
#pragma unroll
        for (int ks = 0; ks < 4; ++ks) {
            const int cb = ks * 32 + hi * 16;
            bf16x8 k0 = *(const bf16x8*)(KsB + l31 * 128        + (cb ^ swz));
            bf16x8 k1 = *(const bf16x8*)(KsB + (l31 + 32) * 128 + (cb ^ swz));
            acc0 = __builtin_amdgcn_mfma_f32_32x32x16_bf16(k0, qf[ks], acc0, 0, 0, 0);
            acc1 = __builtin_amdgcn_mfma_f32_32x32x16_bf16(k1, qf[ks], acc1, 0, 0, 0);
        }

        // ---- per-lane row max over 32 values, then cross-32 combine ----
        float red[8];
#pragma unroll
        for (int i = 0; i < 8; ++i)
            red[i] = fmaxf(fmaxf(acc0[i], acc0[i + 8]), fmaxf(acc1[i], acc1[i + 8]));
#pragma unroll
        for (int i = 0; i < 4; ++i) red[i] = fmaxf(red[i], red[i + 4]);
        float mx = fmaxf(fmaxf(red[0], red[1]), fmaxf(red[2], red[3]));
        mx = fmaxf(mx, xor32f(mx, bpidx));

        // ---- defer-max (T13): rescale only when max grows past threshold ----
        if (__any(mx > mrow + 8.0f)) {
            const float mn = fmaxf(mrow, mx);
            const float alpha = EXP2F(mrow - mn);
            mrow = mn;
            lrowv *= alpha;
#pragma unroll
            for (int r = 0; r < 16; ++r) { O0[r] *= alpha; O1[r] *= alpha; }
        }

        // ---- p = exp2(s - m) ----
#pragma unroll
        for (int r = 0; r < 16; ++r) acc0[r] = EXP2F(acc0[r] - mrow);
#pragma unroll
        for (int r = 0; r < 16; ++r) acc1[r] = EXP2F(acc1[r] - mrow);

        // ---- P -> bf16 via explicit casts; row-sum from ROUNDED values ----
        int wd0[8], wd1[8];
        float ps = 0.f;
#pragma unroll
        for (int s = 0; s < 8; ++s) {
            bf16 e0 = (bf16)acc0[2 * s], o0 = (bf16)acc0[2 * s + 1];
            bf16 e1 = (bf16)acc1[2 * s], o1 = (bf16)acc1[2 * s + 1];
            ps += (float)e0 + (float)o0 + (float)e1 + (float)o1;
            wd0[s] = pack_bf16(e0, o0);
            wd1[s] = pack_bf16(e1, o1);
        }
        ps += xor32f(ps, bpidx);
        lrowv += ps;

        // ---- build PV B-frag words: cross-lane^32 exchange, 2 bpermutes/ks
        //      (pre-select sent value: hi lane sends p0/p1, lo lane sends p2/p3)
        //      word t must hold keys {ks*16 + hi*8 + 2t, +1}
#pragma unroll
        for (int ks = 0; ks < 4; ++ks) {
            const int s0 = (ks & 1) * 4;
            int p0, p1, p2, p3;
            if (ks < 2) { p0 = wd0[s0]; p1 = wd0[s0 + 1]; p2 = wd0[s0 + 2]; p3 = wd0[s0 + 3]; }
            else        { p0 = wd1[s0]; p1 = wd1[s0 + 1]; p2 = wd1[s0 + 2]; p3 = wd1[s0 + 3]; }
            const int rx = xor32i(hi ? p0 : p2, bpidx);  // lo gets partner p0; hi gets partner p2
            const int ry = xor32i(hi ? p1 : p3, bpidx);  // lo gets partner p1; hi gets partner p3
            i32x4 pw = { hi ? rx : p0, hi ? ry : p1, hi ? p2 : rx, hi ? p3 : ry };
            bf16x8 pa = __builtin_bit_cast(bf16x8, pw);

            const int cb = ks * 32 + hi * 16;
            bf16x8 v0 = *(const bf16x8*)(VsB + l31 * 128        + (cb ^ swz));
            bf16x8 v1 = *(const bf16x8*)(VsB + (l31 + 32) * 128 + (cb ^ swz));
            O0 = __builtin_amdgcn_mfma_f32_32x32x16_bf16(v0, pa, O0, 0, 0, 0);
            O1 = __builtin_amdgcn_mfma_f32_32x32x16_bf16(v1, pa, O1, 0, 0, 0);
        }
        __syncthreads();
    }

    // ---- epilogue: per-lane normalize, packed bf16x4 stores ----
    const float rinv = RCPF(lrowv);
    bf16* og = out + ((size_t)b * S_ + qt * 128 + w * 32 + l31) * D_ + h * DK_;
#pragma unroll
    for (int rr = 0; rr < 4; ++rr) {
        bf16x4 o0 = { (bf16)(O0[rr * 4 + 0] * rinv), (bf16)(O0[rr * 4 + 1] * rinv),
                      (bf16)(O0[rr * 4 + 2] * rinv), (bf16)(O0[rr * 4 + 3] * rinv) };
        bf16x4 o1 = { (bf16)(O1[rr * 4 + 0] * rinv), (bf16)(O1[rr * 4 + 1] * rinv),
                      (bf16)(O1[rr * 4 + 2] * rinv), (bf16)(O1[rr * 4 + 3] * rinv) };
        *(bf16x4*)(og + rr * 8 + hi * 4)      = o0;
        *(bf16x4*)(og + 32 + rr * 8 + hi * 4) = o1;
    }
}

// ---------------------------------------------------------------------------
extern "C" void kernel_launch(void* const* d_in, const int* in_sizes, int n_in,
                              void* d_out, int out_size, void* d_ws, size_t ws_size,
                              hipStream_t stream) {
    const float* q    = (const float*)d_in[0];
    const float* k    = (const float*)d_in[1];
    const float* v    = (const float*)d_in[2];
    const int*   mask = (const int*)d_in[3];
    const float* WQw  = (const float*)d_in[4];
    const float* WQb  = (const float*)d_in[5];
    const float* WKw  = (const float*)d_in[6];
    const float* WKb  = (const float*)d_in[7];
    const float* WVw  = (const float*)d_in[8];
    const float* WVb  = (const float*)d_in[9];
    const float* WOw  = (const float*)d_in[10];
    const float* WOb  = (const float*)d_in[11];

    bf16* ws = (bf16*)d_ws;
    bf16* qb  = ws;              // A8  (later aliased by maskf, lower half)
    bf16* kb  = qb + A8;         // A8  (later aliased by maskf, upper half)
    bf16* vb  = kb + A8;         // A8  (later aliased by AO)
    bf16* wqb = vb + A8;         // W1 x4
    bf16* wkb = wqb + W1;
    bf16* wvb = wkb + W1;
    bf16* wob = wvb + W1;
    bf16* Qp  = wob + W1;        // [B,H,S,DK]
    bf16* Kp  = Qp + A8;         // [B,H,S,DK]
    bf16* Vp  = Kp + A8;         // [B,H,DK,S] transposed
    float* maskf = (float*)qb;   // alias: 32 MB over qb+kb (dead after QKV GEMM)
    bf16* AO     = vb;           // alias: vb dead after V-GEMM

    cvt_all<<<dim3(14336), 256, 0, stream>>>(q, k, v, WQw, WKw, WVw, WOw, ws);

    qkv_gemm<<<dim3(1536), 256, 0, stream>>>(qb, kb, vb, wqb, wkb, wvb,
                                             WQb, WKb, WVb, Qp, Kp, Vp, QSCALE);

    mask_cvt<<<dim3(1024), 256, 0, stream>>>(mask, maskf);

    attn_mfma<<<dim3(1024), 256, 0, stream>>>(Qp, Kp, Vp, maskf, AO);

    gemm_out<<<dim3(M_ / 128, D_ / 128), 256, 0, stream>>>(AO, wob, WOb, (float*)d_out);
}